// Round 10
// baseline (244.695 us; speedup 1.0000x reference)
//
#include <hip/hip_runtime.h>
#include <hip/hip_bf16.h>

typedef unsigned short u16;
typedef unsigned int u32;
typedef float f32x4 __attribute__((ext_vector_type(4)));
typedef short bf16x8 __attribute__((ext_vector_type(8)));   // 8 bf16 as i16 (4 VGPRs)

#define LOG2E 1.4426950408889634f

static __device__ __forceinline__ u16 f2bf(float f){
  __hip_bfloat16 h = __float2bfloat16(f);
  return __builtin_bit_cast(u16, h);
}
static __device__ __forceinline__ float bf2f(u16 u){
  __hip_bfloat16 h = __builtin_bit_cast(__hip_bfloat16, u);
  return __bfloat162float(h);
}
static __device__ __forceinline__ float fexp2(float x){
#if __has_builtin(__builtin_amdgcn_exp2f)
  return __builtin_amdgcn_exp2f(x);
#else
  return exp2f(x);
#endif
}
static __device__ __forceinline__ u32 pack2(float a, float b){
  return (u32)f2bf(a) | ((u32)f2bf(b) << 16);
}
static __device__ __forceinline__ f32x4 mf(bf16x8 a, bf16x8 b, f32x4 c){
  return __builtin_amdgcn_mfma_f32_16x16x32_bf16(a, b, c, 0, 0, 0);
}

// ---------------------------------------------------------------------------
// Kernel 1: QKV projection, n-on-lanes. grid (32, 4, 3) x 128 threads.
// Lane owns one n (consecutive lanes = consecutive n -> 256B/512B coalesced
// x loads); c is the serial loop; W/bias indices are wave-uniform -> scalar
// (s_load / K$) broadcasts. Each lane ends with all 16 sums -> no reduction,
// fully coalesced packed stores. 16 FMA chains/lane hide FMA latency.
// ---------------------------------------------------------------------------
__global__ __launch_bounds__(128, 8) void qkv_kernel(
    const float* __restrict__ x,
    const float* __restrict__ Wq, const float* __restrict__ bq,
    const float* __restrict__ Wk, const float* __restrict__ bk,
    const float* __restrict__ Wv, const float* __restrict__ bv,
    u16* __restrict__ qh, u16* __restrict__ ql,
    u16* __restrict__ kcat, u16* __restrict__ vT)
{
  int t = threadIdx.x;
  int nt = blockIdx.x, b = blockIdx.y, m = blockIdx.z;
  const float* __restrict__ W    = (m==0) ? Wq : (m==1) ? Wk : Wv;
  const float* __restrict__ bias = (m==0) ? bq : (m==1) ? bk : bv;
  int n = nt*128 + t;
  const float* xb = x + ((size_t)b << 20) + n;
  float acc[16];
  #pragma unroll
  for (int d = 0; d < 16; ++d) acc[d] = 0.f;
  #pragma unroll 8
  for (int c = 0; c < 256; ++c) {
    float xv = xb[(size_t)c << 12];
    #pragma unroll
    for (int d = 0; d < 16; ++d)
      acc[d] = __builtin_fmaf(W[d*256 + c], xv, acc[d]);
  }
  if (m == 2) {
    // vT[b*16+d][n]: per-d stores are coalesced across lanes (consecutive n)
    #pragma unroll
    for (int d = 0; d < 16; ++d)
      vT[((size_t)(b*16 + d) << 12) + n] = f2bf(acc[d] + bias[d]);
  } else {
    alignas(16) u16 hi[16]; alignas(16) u16 lo[16];
    #pragma unroll
    for (int d = 0; d < 16; ++d) {
      float v_ = acc[d] + bias[d];
      u16 h = f2bf(v_);
      hi[d] = h;
      lo[d] = f2bf(v_ - bf2f(h));
    }
    if (m == 0) {
      // qh/ql rows of 16 u16 per n
      int4* dq = (int4*)(qh + (((size_t)(b << 12) + n) << 4));
      dq[0] = ((int4*)hi)[0]; dq[1] = ((int4*)hi)[1];
      int4* dl = (int4*)(ql + (((size_t)(b << 12) + n) << 4));
      dl[0] = ((int4*)lo)[0]; dl[1] = ((int4*)lo)[1];
    } else {
      // kcat rows [kh(16)|kl(16)] per n
      int4* dk = (int4*)(kcat + (((size_t)(b << 12) + n) << 5));
      dk[0] = ((int4*)hi)[0]; dk[1] = ((int4*)hi)[1];
      dk[2] = ((int4*)lo)[0]; dk[3] = ((int4*)lo)[1];
    }
  }
}

// ---------------------------------------------------------------------------
// Kernel 2: flash attention (no-max softmax, split-K = gridDim.z).
// Explicit 2-chunk register pipeline: fA/fB Frag sets, each reloaded 2 chunks
// ahead right after its compute; separate LDS P-tiles per parity so the two
// chains share nothing. Scores fp32-accurate via Dekker split (loop-invariant
// B-side mask). av accumulated as MFMA C; stored as one float4 per lane.
// ---------------------------------------------------------------------------
struct Frags { bf16x8 ac0,ac1,ac2,ac3, v0,v1; };

static __device__ __forceinline__ Frags loadFrags(
  const u16* __restrict__ kc, const u16* __restrict__ vp,
  int kb, int i, int g)
{
  Frags f;
  const u16* a0 = kc + (kb + i)*32 + g*8;
  f.ac0 = *(const bf16x8*)(a0);
  f.ac1 = *(const bf16x8*)(a0 + 512);
  f.ac2 = *(const bf16x8*)(a0 + 1024);
  f.ac3 = *(const bf16x8*)(a0 + 1536);
  const u16* v0p = vp + kb + g*8;
  f.v0 = *(const bf16x8*)(v0p);
  f.v1 = *(const bf16x8*)(v0p + 32);
  return f;
}

static __device__ __forceinline__ void computeChunk(
  const Frags& cu, char* tile, bf16x8 Bqh, bf16x8 Bql,
  f32x4& av, float& lsum, int rowb, int mi, int g)
{
  f32x4 z4 = {0.f,0.f,0.f,0.f};
  f32x4 s0 = mf(cu.ac0, Bqh, z4); s0 = mf(cu.ac0, Bql, s0);
  f32x4 s1 = mf(cu.ac1, Bqh, z4); s1 = mf(cu.ac1, Bql, s1);
  f32x4 s2 = mf(cu.ac2, Bqh, z4); s2 = mf(cu.ac2, Bql, s2);
  f32x4 s3 = mf(cu.ac3, Bqh, z4); s3 = mf(cu.ac3, Bql, s3);
  f32x4 p0, p1, p2, p3;
  #pragma unroll
  for (int r = 0; r < 4; ++r) {
    p0[r] = fexp2(s0[r]*LOG2E);
    p1[r] = fexp2(s1[r]*LOG2E);
    p2[r] = fexp2(s2[r]*LOG2E);
    p3[r] = fexp2(s3[r]*LOG2E);
  }
  lsum += (p0[0]+p0[1]+p0[2]+p0[3]) + (p1[0]+p1[1]+p1[2]+p1[3])
        + (p2[0]+p2[1]+p2[2]+p2[3]) + (p3[0]+p3[1]+p3[2]+p3[3]);
  // P^T tile: row = query i (128B), byte 2*keylocal, XOR-swizzled by mi.
  *(uint2*)(tile + rowb + (((8*g)      ) ^ mi)) =
      (uint2){ pack2(p0[0], p0[1]), pack2(p0[2], p0[3]) };
  *(uint2*)(tile + rowb + (((8*g) + 32 ) ^ mi)) =
      (uint2){ pack2(p1[0], p1[1]), pack2(p1[2], p1[3]) };
  *(uint2*)(tile + rowb + (((8*g) + 64 ) ^ mi)) =
      (uint2){ pack2(p2[0], p2[1]), pack2(p2[2], p2[3]) };
  *(uint2*)(tile + rowb + (((8*g) + 96 ) ^ mi)) =
      (uint2){ pack2(p3[0], p3[1]), pack2(p3[2], p3[3]) };
  bf16x8 Bp0 = *(const bf16x8*)(tile + rowb + (( 0 + 16*g) ^ mi));
  bf16x8 Bp1 = *(const bf16x8*)(tile + rowb + ((64 + 16*g) ^ mi));
  av = mf(cu.v0, Bp0, av);
  av = mf(cu.v1, Bp1, av);
}

__global__ __launch_bounds__(256, 4) void attn_kernel(
    const u16* __restrict__ qh, const u16* __restrict__ ql,
    const u16* __restrict__ kcat, const u16* __restrict__ vT,
    float* __restrict__ av_part, float* __restrict__ l_part)
{
  __shared__ char plds[4*4096];    // per-wave 2x 16x64 bf16 P^T tiles
  int tid = threadIdx.x, wid = tid >> 6, lane = tid & 63;
  int g = lane >> 4, i = lane & 15;
  int b = blockIdx.y, s = blockIdx.z;
  int nsplit = gridDim.z;
  int iters = 64 / nsplit;               // even for nsplit in {1,2,4,8}
  int qidx = blockIdx.x*64 + wid*16 + i;
  char* myp0 = plds + wid*4096;
  char* myp1 = myp0 + 2048;
  int rowb = i*128;
  int mi = (i & 7) << 4;

  bf16x8 Bqh = *(const bf16x8*)(qh + ((size_t)((b << 12) + qidx))*16 + ((g & 1) << 3));
  bf16x8 Bql = *(const bf16x8*)(ql + ((size_t)((b << 12) + qidx))*16 + ((g & 1) << 3));
  if (g >= 2) {   // loop-invariant B-side mask: [ql|0] over the k=32 dim
    #pragma unroll
    for (int e = 0; e < 8; ++e) Bql[e] = 0;
  }
  const u16* kc = kcat + (size_t)b*4096*32;
  const u16* vp = vT   + ((size_t)(b*16 + i) << 12);

  f32x4 av = {0.f,0.f,0.f,0.f};
  float lsum = 0.f;
  int kb0 = s*(iters*64);
  Frags fA = loadFrags(kc, vp, kb0,      i, g);
  Frags fB = loadFrags(kc, vp, kb0 + 64, i, g);
  for (int it = 0; it < iters; it += 2) {
    computeChunk(fA, myp0, Bqh, Bql, av, lsum, rowb, mi, g);
    if (it + 2 < iters) fA = loadFrags(kc, vp, kb0 + (it+2)*64, i, g);
    computeChunk(fB, myp1, Bqh, Bql, av, lsum, rowb, mi, g);
    if (it + 3 < iters) fB = loadFrags(kc, vp, kb0 + (it+3)*64, i, g);
  }
  float lt = lsum;
  lt += __shfl_xor(lt, 16, 64);
  lt += __shfl_xor(lt, 32, 64);
  // av_part layout: [s][b][n][16] -> one float4 store per lane
  float* avp = av_part + ((size_t)(s*4 + b) << 16);
  float4 st = { av[0], av[1], av[2], av[3] };
  *(float4*)(avp + ((size_t)qidx << 4) + (g << 2)) = st;
  if (lane < 16)
    l_part[((size_t)(s*4 + b) << 12) + qidx] = lt;
}

// ---------------------------------------------------------------------------
// Kernel 3: merge key-splits + output projection. grid (16,16,4) x 256.
// av_part is [s][b][n][16] -> float4 reads.
// ---------------------------------------------------------------------------
__global__ __launch_bounds__(256, 4) void outproj_kernel(
    const float* __restrict__ av_part, const float* __restrict__ l_part,
    const float* __restrict__ Wo, const float* __restrict__ bo,
    float* __restrict__ out, int nsplit)
{
  __shared__ float wl[16][16];
  __shared__ float bol[16];
  int t = threadIdx.x;
  int ct = blockIdx.x, ntile = blockIdx.y, b = blockIdx.z;
  wl[t >> 4][t & 15] = Wo[(ct*16 + (t >> 4))*16 + (t & 15)];
  if (t < 16) bol[t] = bo[ct*16 + t];
  __syncthreads();
  int n = ntile*256 + t;
  float lsum = 0.f;
  for (int s = 0; s < nsplit; ++s)
    lsum += l_part[((size_t)(s*4 + b) << 12) + n];
  float inv = 1.f / lsum;
  float avv[16];
  #pragma unroll
  for (int d = 0; d < 16; ++d) avv[d] = 0.f;
  for (int s = 0; s < nsplit; ++s) {
    const float4* ap = (const float4*)(av_part + ((size_t)(s*4 + b) << 16)
                                      + ((size_t)n << 4));
    #pragma unroll
    for (int q_ = 0; q_ < 4; ++q_) {
      float4 a = ap[q_];
      avv[q_*4+0] += a.x; avv[q_*4+1] += a.y;
      avv[q_*4+2] += a.z; avv[q_*4+3] += a.w;
    }
  }
  #pragma unroll
  for (int d = 0; d < 16; ++d) avv[d] *= inv;
  #pragma unroll
  for (int cc = 0; cc < 16; ++cc) {
    float o = bol[cc];
    #pragma unroll
    for (int d = 0; d < 16; ++d) o += wl[cc][d] * avv[d];
    out[((size_t)(b*256 + ct*16 + cc) << 12) + n] = o;
  }
}

extern "C" void kernel_launch(void* const* d_in, const int* in_sizes, int n_in,
                              void* d_out, int out_size, void* d_ws, size_t ws_size,
                              hipStream_t stream) {
  (void)in_sizes; (void)n_in; (void)out_size;
  const float* x  = (const float*)d_in[0];
  const float* Wq = (const float*)d_in[1];
  const float* bq = (const float*)d_in[2];
  const float* Wk = (const float*)d_in[3];
  const float* bk = (const float*)d_in[4];
  const float* Wv = (const float*)d_in[5];
  const float* bv = (const float*)d_in[6];
  const float* Wo = (const float*)d_in[7];
  const float* bo = (const float*)d_in[8];
  float* out = (float*)d_out;
  char* ws = (char*)d_ws;

  // Fixed buffers: qh 512K, ql 512K, kcat 1M, vT 512K = 2.5 MB
  const size_t fixed = 2621440;
  const size_t per_split = 1048576 + 65536;   // av (1MB) + l (64KB) per split
  int nsplit = 8;
  while (nsplit > 1 && fixed + (size_t)nsplit*per_split > ws_size) nsplit >>= 1;

  u16* qh   = (u16*)(ws + 0);
  u16* ql   = (u16*)(ws + 524288);
  u16* kcat = (u16*)(ws + 1048576);
  u16* vT   = (u16*)(ws + 2097152);
  float* av_part = (float*)(ws + fixed);
  float* l_part  = (float*)(ws + fixed + (size_t)nsplit*1048576);

  qkv_kernel<<<dim3(32, 4, 3), dim3(128), 0, stream>>>(
      x, Wq, bq, Wk, bk, Wv, bv, qh, ql, kcat, vT);
  attn_kernel<<<dim3(64, 4, nsplit), dim3(256), 0, stream>>>(
      qh, ql, kcat, vT, av_part, l_part);
  outproj_kernel<<<dim3(16, 16, 4), dim3(256), 0, stream>>>(
      av_part, l_part, Wo, bo, out, nsplit);
}

// Round 12
// 153.045 us; speedup vs baseline: 1.5988x; 1.5988x over previous
//
#include <hip/hip_runtime.h>
#include <hip/hip_bf16.h>

typedef unsigned short u16;
typedef unsigned int u32;
typedef float f32x4 __attribute__((ext_vector_type(4)));
typedef short bf16x8 __attribute__((ext_vector_type(8)));   // 8 bf16 as i16 (4 VGPRs)

#define LOG2E 1.4426950408889634f

static __device__ __forceinline__ u16 f2bf(float f){
  __hip_bfloat16 h = __float2bfloat16(f);
  return __builtin_bit_cast(u16, h);
}
static __device__ __forceinline__ float bf2f(u16 u){
  __hip_bfloat16 h = __builtin_bit_cast(__hip_bfloat16, u);
  return __bfloat162float(h);
}
static __device__ __forceinline__ float fexp2(float x){
#if __has_builtin(__builtin_amdgcn_exp2f)
  return __builtin_amdgcn_exp2f(x);
#else
  return exp2f(x);
#endif
}
static __device__ __forceinline__ u32 pack2(float a, float b){
  return (u32)f2bf(a) | ((u32)f2bf(b) << 16);
}
static __device__ __forceinline__ f32x4 mf(bf16x8 a, bf16x8 b, f32x4 c){
  return __builtin_amdgcn_mfma_f32_16x16x32_bf16(a, b, c, 0, 0, 0);
}

// ---------------------------------------------------------------------------
// Kernel 1: QKV projection, o-split. grid (16 nt, 4 b, 6 mo) x 256 threads.
// mo = m*2 + half: block computes 8 outputs (o = half*8..+8) of matrix m for
// 256 consecutive n. W-slice [8][256] fp32 staged in LDS (wave-uniform
// broadcast reads -> no K$ thrash, no conflicts). Thread owns one n, 8 accs;
// inner loop: 4 coalesced x loads + 8 ds_read_b128 + 32 FMA. 1536 waves.
// ---------------------------------------------------------------------------
__global__ __launch_bounds__(256, 8) void qkv_kernel(
    const float* __restrict__ x,
    const float* __restrict__ Wq, const float* __restrict__ bq,
    const float* __restrict__ Wk, const float* __restrict__ bk,
    const float* __restrict__ Wv, const float* __restrict__ bv,
    u16* __restrict__ qh, u16* __restrict__ ql,
    u16* __restrict__ kcat, u16* __restrict__ vT)
{
  __shared__ float wlds[8*256];    // [o=8][c=256]
  int t = threadIdx.x;
  int nt = blockIdx.x, b = blockIdx.y, mo = blockIdx.z;
  int m = mo >> 1, half = mo & 1, d0 = half*8;
  const float* __restrict__ W    = (m==0) ? Wq : (m==1) ? Wk : Wv;
  const float* __restrict__ bias = (m==0) ? bq : (m==1) ? bk : bv;
  #pragma unroll
  for (int k = 0; k < 8; ++k) {
    int idx = k*256 + t;                 // o = k, c = t  (coalesced)
    wlds[idx] = W[(d0 + k)*256 + t];
  }
  __syncthreads();
  int n = nt*256 + t;
  const float* xb = x + ((size_t)b << 20) + n;
  const float4* wl4 = (const float4*)wlds;
  float acc[8];
  #pragma unroll
  for (int o = 0; o < 8; ++o) acc[o] = 0.f;
  #pragma unroll 2
  for (int c4 = 0; c4 < 64; ++c4) {
    int c = c4*4;
    float x0 = xb[(size_t)(c+0) << 12];
    float x1 = xb[(size_t)(c+1) << 12];
    float x2 = xb[(size_t)(c+2) << 12];
    float x3 = xb[(size_t)(c+3) << 12];
    float4 w0 = wl4[0*64 + c4], w1 = wl4[1*64 + c4];
    float4 w2 = wl4[2*64 + c4], w3 = wl4[3*64 + c4];
    float4 w4 = wl4[4*64 + c4], w5 = wl4[5*64 + c4];
    float4 w6 = wl4[6*64 + c4], w7 = wl4[7*64 + c4];
    acc[0] += w0.x*x0 + w0.y*x1 + w0.z*x2 + w0.w*x3;
    acc[1] += w1.x*x0 + w1.y*x1 + w1.z*x2 + w1.w*x3;
    acc[2] += w2.x*x0 + w2.y*x1 + w2.z*x2 + w2.w*x3;
    acc[3] += w3.x*x0 + w3.y*x1 + w3.z*x2 + w3.w*x3;
    acc[4] += w4.x*x0 + w4.y*x1 + w4.z*x2 + w4.w*x3;
    acc[5] += w5.x*x0 + w5.y*x1 + w5.z*x2 + w5.w*x3;
    acc[6] += w6.x*x0 + w6.y*x1 + w6.z*x2 + w6.w*x3;
    acc[7] += w7.x*x0 + w7.y*x1 + w7.z*x2 + w7.w*x3;
  }
  if (m == 2) {
    // vT[b*16 + d0+j][n]: 2B x 256 consecutive n = contiguous 512B per plane
    #pragma unroll
    for (int j = 0; j < 8; ++j)
      vT[((size_t)(b*16 + d0 + j) << 12) + n] = f2bf(acc[j] + bias[d0 + j]);
  } else {
    alignas(16) u16 hi[8]; alignas(16) u16 lo[8];
    #pragma unroll
    for (int j = 0; j < 8; ++j) {
      float v_ = acc[j] + bias[d0 + j];
      u16 h = f2bf(v_);
      hi[j] = h;
      lo[j] = f2bf(v_ - bf2f(h));
    }
    if (m == 0) {
      // qh/ql rows of 16 u16 per n; this block fills the d0..d0+8 half
      *(int4*)(qh + (((size_t)(b << 12) + n) << 4) + d0) = *(const int4*)hi;
      *(int4*)(ql + (((size_t)(b << 12) + n) << 4) + d0) = *(const int4*)lo;
    } else {
      // kcat rows [kh(16)|kl(16)] per n
      *(int4*)(kcat + (((size_t)(b << 12) + n) << 5) + d0)      = *(const int4*)hi;
      *(int4*)(kcat + (((size_t)(b << 12) + n) << 5) + 16 + d0) = *(const int4*)lo;
    }
  }
}

// ---------------------------------------------------------------------------
// Kernel 2: flash attention (no-max softmax, split-K = gridDim.z).
// Explicit 2-chunk register pipeline: fA/fB Frag sets, each reloaded 2 chunks
// ahead right after its compute; separate LDS P-tiles per parity so the two
// chains share nothing. Scores fp32-accurate via Dekker split (loop-invariant
// B-side mask). av accumulated as MFMA C; stored as one float4 per lane.
// ---------------------------------------------------------------------------
struct Frags { bf16x8 ac0,ac1,ac2,ac3, v0,v1; };

static __device__ __forceinline__ Frags loadFrags(
  const u16* __restrict__ kc, const u16* __restrict__ vp,
  int kb, int i, int g)
{
  Frags f;
  const u16* a0 = kc + (kb + i)*32 + g*8;
  f.ac0 = *(const bf16x8*)(a0);
  f.ac1 = *(const bf16x8*)(a0 + 512);
  f.ac2 = *(const bf16x8*)(a0 + 1024);
  f.ac3 = *(const bf16x8*)(a0 + 1536);
  const u16* v0p = vp + kb + g*8;
  f.v0 = *(const bf16x8*)(v0p);
  f.v1 = *(const bf16x8*)(v0p + 32);
  return f;
}

static __device__ __forceinline__ void computeChunk(
  const Frags& cu, char* tile, bf16x8 Bqh, bf16x8 Bql,
  f32x4& av, float& lsum, int rowb, int mi, int g)
{
  f32x4 z4 = {0.f,0.f,0.f,0.f};
  f32x4 s0 = mf(cu.ac0, Bqh, z4); s0 = mf(cu.ac0, Bql, s0);
  f32x4 s1 = mf(cu.ac1, Bqh, z4); s1 = mf(cu.ac1, Bql, s1);
  f32x4 s2 = mf(cu.ac2, Bqh, z4); s2 = mf(cu.ac2, Bql, s2);
  f32x4 s3 = mf(cu.ac3, Bqh, z4); s3 = mf(cu.ac3, Bql, s3);
  f32x4 p0, p1, p2, p3;
  #pragma unroll
  for (int r = 0; r < 4; ++r) {
    p0[r] = fexp2(s0[r]*LOG2E);
    p1[r] = fexp2(s1[r]*LOG2E);
    p2[r] = fexp2(s2[r]*LOG2E);
    p3[r] = fexp2(s3[r]*LOG2E);
  }
  lsum += (p0[0]+p0[1]+p0[2]+p0[3]) + (p1[0]+p1[1]+p1[2]+p1[3])
        + (p2[0]+p2[1]+p2[2]+p2[3]) + (p3[0]+p3[1]+p3[2]+p3[3]);
  // P^T tile: row = query i (128B), byte 2*keylocal, XOR-swizzled by mi.
  *(uint2*)(tile + rowb + (((8*g)      ) ^ mi)) =
      (uint2){ pack2(p0[0], p0[1]), pack2(p0[2], p0[3]) };
  *(uint2*)(tile + rowb + (((8*g) + 32 ) ^ mi)) =
      (uint2){ pack2(p1[0], p1[1]), pack2(p1[2], p1[3]) };
  *(uint2*)(tile + rowb + (((8*g) + 64 ) ^ mi)) =
      (uint2){ pack2(p2[0], p2[1]), pack2(p2[2], p2[3]) };
  *(uint2*)(tile + rowb + (((8*g) + 96 ) ^ mi)) =
      (uint2){ pack2(p3[0], p3[1]), pack2(p3[2], p3[3]) };
  bf16x8 Bp0 = *(const bf16x8*)(tile + rowb + (( 0 + 16*g) ^ mi));
  bf16x8 Bp1 = *(const bf16x8*)(tile + rowb + ((64 + 16*g) ^ mi));
  av = mf(cu.v0, Bp0, av);
  av = mf(cu.v1, Bp1, av);
}

__global__ __launch_bounds__(256, 4) void attn_kernel(
    const u16* __restrict__ qh, const u16* __restrict__ ql,
    const u16* __restrict__ kcat, const u16* __restrict__ vT,
    float* __restrict__ av_part, float* __restrict__ l_part)
{
  __shared__ char plds[4*4096];    // per-wave 2x 16x64 bf16 P^T tiles
  int tid = threadIdx.x, wid = tid >> 6, lane = tid & 63;
  int g = lane >> 4, i = lane & 15;
  int b = blockIdx.y, s = blockIdx.z;
  int nsplit = gridDim.z;
  int iters = 64 / nsplit;               // even for nsplit in {1,2,4,8}
  int qidx = blockIdx.x*64 + wid*16 + i;
  char* myp0 = plds + wid*4096;
  char* myp1 = myp0 + 2048;
  int rowb = i*128;
  int mi = (i & 7) << 4;

  bf16x8 Bqh = *(const bf16x8*)(qh + ((size_t)((b << 12) + qidx))*16 + ((g & 1) << 3));
  bf16x8 Bql = *(const bf16x8*)(ql + ((size_t)((b << 12) + qidx))*16 + ((g & 1) << 3));
  if (g >= 2) {   // loop-invariant B-side mask: [ql|0] over the k=32 dim
    #pragma unroll
    for (int e = 0; e < 8; ++e) Bql[e] = 0;
  }
  const u16* kc = kcat + (size_t)b*4096*32;
  const u16* vp = vT   + ((size_t)(b*16 + i) << 12);

  f32x4 av = {0.f,0.f,0.f,0.f};
  float lsum = 0.f;
  int kb0 = s*(iters*64);
  Frags fA = loadFrags(kc, vp, kb0,      i, g);
  Frags fB = loadFrags(kc, vp, kb0 + 64, i, g);
  for (int it = 0; it < iters; it += 2) {
    computeChunk(fA, myp0, Bqh, Bql, av, lsum, rowb, mi, g);
    if (it + 2 < iters) fA = loadFrags(kc, vp, kb0 + (it+2)*64, i, g);
    computeChunk(fB, myp1, Bqh, Bql, av, lsum, rowb, mi, g);
    if (it + 3 < iters) fB = loadFrags(kc, vp, kb0 + (it+3)*64, i, g);
  }
  float lt = lsum;
  lt += __shfl_xor(lt, 16, 64);
  lt += __shfl_xor(lt, 32, 64);
  // av_part layout: [s][b][n][16] -> one float4 store per lane
  float* avp = av_part + ((size_t)(s*4 + b) << 16);
  float4 st = { av[0], av[1], av[2], av[3] };
  *(float4*)(avp + ((size_t)qidx << 4) + (g << 2)) = st;
  if (lane < 16)
    l_part[((size_t)(s*4 + b) << 12) + qidx] = lt;
}

// ---------------------------------------------------------------------------
// Kernel 3: merge key-splits + output projection. grid (16,16,4) x 256.
// av_part is [s][b][n][16] -> float4 reads.
// ---------------------------------------------------------------------------
__global__ __launch_bounds__(256, 4) void outproj_kernel(
    const float* __restrict__ av_part, const float* __restrict__ l_part,
    const float* __restrict__ Wo, const float* __restrict__ bo,
    float* __restrict__ out, int nsplit)
{
  __shared__ float wl[16][16];
  __shared__ float bol[16];
  int t = threadIdx.x;
  int ct = blockIdx.x, ntile = blockIdx.y, b = blockIdx.z;
  wl[t >> 4][t & 15] = Wo[(ct*16 + (t >> 4))*16 + (t & 15)];
  if (t < 16) bol[t] = bo[ct*16 + t];
  __syncthreads();
  int n = ntile*256 + t;
  float lsum = 0.f;
  for (int s = 0; s < nsplit; ++s)
    lsum += l_part[((size_t)(s*4 + b) << 12) + n];
  float inv = 1.f / lsum;
  float avv[16];
  #pragma unroll
  for (int d = 0; d < 16; ++d) avv[d] = 0.f;
  for (int s = 0; s < nsplit; ++s) {
    const float4* ap = (const float4*)(av_part + ((size_t)(s*4 + b) << 16)
                                      + ((size_t)n << 4));
    #pragma unroll
    for (int q_ = 0; q_ < 4; ++q_) {
      float4 a = ap[q_];
      avv[q_*4+0] += a.x; avv[q_*4+1] += a.y;
      avv[q_*4+2] += a.z; avv[q_*4+3] += a.w;
    }
  }
  #pragma unroll
  for (int d = 0; d < 16; ++d) avv[d] *= inv;
  #pragma unroll
  for (int cc = 0; cc < 16; ++cc) {
    float o = bol[cc];
    #pragma unroll
    for (int d = 0; d < 16; ++d) o += wl[cc][d] * avv[d];
    out[((size_t)(b*256 + ct*16 + cc) << 12) + n] = o;
  }
}

extern "C" void kernel_launch(void* const* d_in, const int* in_sizes, int n_in,
                              void* d_out, int out_size, void* d_ws, size_t ws_size,
                              hipStream_t stream) {
  (void)in_sizes; (void)n_in; (void)out_size;
  const float* x  = (const float*)d_in[0];
  const float* Wq = (const float*)d_in[1];
  const float* bq = (const float*)d_in[2];
  const float* Wk = (const float*)d_in[3];
  const float* bk = (const float*)d_in[4];
  const float* Wv = (const float*)d_in[5];
  const float* bv = (const float*)d_in[6];
  const float* Wo = (const float*)d_in[7];
  const float* bo = (const float*)d_in[8];
  float* out = (float*)d_out;
  char* ws = (char*)d_ws;

  // Fixed buffers: qh 512K, ql 512K, kcat 1M, vT 512K = 2.5 MB
  const size_t fixed = 2621440;
  const size_t per_split = 1048576 + 65536;   // av (1MB) + l (64KB) per split
  int nsplit = 8;
  while (nsplit > 1 && fixed + (size_t)nsplit*per_split > ws_size) nsplit >>= 1;

  u16* qh   = (u16*)(ws + 0);
  u16* ql   = (u16*)(ws + 524288);
  u16* kcat = (u16*)(ws + 1048576);
  u16* vT   = (u16*)(ws + 2097152);
  float* av_part = (float*)(ws + fixed);
  float* l_part  = (float*)(ws + fixed + (size_t)nsplit*1048576);

  qkv_kernel<<<dim3(16, 4, 6), dim3(256), 0, stream>>>(
      x, Wq, bq, Wk, bk, Wv, bv, qh, ql, kcat, vT);
  attn_kernel<<<dim3(64, 4, nsplit), dim3(256), 0, stream>>>(
      qh, ql, kcat, vT, av_part, l_part);
  outproj_kernel<<<dim3(16, 16, 4), dim3(256), 0, stream>>>(
      av_part, l_part, Wo, bo, out, nsplit);
}